// Round 1
// baseline (196.654 us; speedup 1.0000x reference)
//
#include <hip/hip_runtime.h>

// Problem constants (from reference): B,R,C,H,W = 4,2,19,256,512
constexpr int B = 4, R = 2, C = 19, H = 256, W = 512;
constexpr int HW = H * W;

__global__ __launch_bounds__(256) void mc_warp_kernel(
    const float* __restrict__ pred,   // [B,R,C,H,W]
    const float* __restrict__ mv,     // [B,R,2,H,W] quarter-pel
    const float* __restrict__ wgt,    // [B,R,1,H,W]
    float* __restrict__ out)          // [B,C,H,W]
{
    int idx = blockIdx.x * blockDim.x + threadIdx.x;   // b*HW + y*W + x
    if (idx >= B * HW) return;
    int x = idx & (W - 1);
    int y = (idx >> 9) & (H - 1);     // W = 512 = 2^9
    int b = idx / HW;
    int pix = y * W + x;

    int   lin[R][4];
    float wt[R][4];

    #pragma unroll
    for (int r = 0; r < R; ++r) {
        const float* mvb = mv + ((size_t)(b * R + r) * 2) * HW + pix;
        float mx = mvb[0]  * 0.25f;   // quarter-pel -> pixel, x displacement
        float my = mvb[HW] * 0.25f;   // y displacement
        float gx = (float)x + mx;
        float gy = (float)y + my;
        float fx0 = floorf(gx), fy0 = floorf(gy);
        float wx1 = gx - fx0, wx0 = 1.0f - wx1;
        float wy1 = gy - fy0, wy0 = 1.0f - wy1;
        float wr = wgt[(size_t)(b * R + r) * HW + pix];

        int ix0 = (int)fx0, iy0 = (int)fy0;
        int ix1 = ix0 + 1,  iy1 = iy0 + 1;
        bool vx0 = (ix0 >= 0) && (ix0 <= W - 1);
        bool vx1 = (ix1 >= 0) && (ix1 <= W - 1);
        bool vy0 = (iy0 >= 0) && (iy0 <= H - 1);
        bool vy1 = (iy1 >= 0) && (iy1 <= H - 1);
        int cx0 = min(max(ix0, 0), W - 1), cx1 = min(max(ix1, 0), W - 1);
        int cy0 = min(max(iy0, 0), H - 1), cy1 = min(max(iy1, 0), H - 1);

        lin[r][0] = cy0 * W + cx0;  wt[r][0] = wy0 * wx0 * ((vy0 && vx0) ? wr : 0.0f);
        lin[r][1] = cy0 * W + cx1;  wt[r][1] = wy0 * wx1 * ((vy0 && vx1) ? wr : 0.0f);
        lin[r][2] = cy1 * W + cx0;  wt[r][2] = wy1 * wx0 * ((vy1 && vx0) ? wr : 0.0f);
        lin[r][3] = cy1 * W + cx1;  wt[r][3] = wy1 * wx1 * ((vy1 && vx1) ? wr : 0.0f);
    }

    const float* p0 = pred + (size_t)(b * R + 0) * C * HW;
    const float* p1 = pred + (size_t)(b * R + 1) * C * HW;
    float* ob = out + (size_t)b * C * HW + pix;

    for (int c = 0; c < C; ++c) {
        const float* pc0 = p0 + (size_t)c * HW;
        const float* pc1 = p1 + (size_t)c * HW;
        float acc = 0.0f;
        #pragma unroll
        for (int t = 0; t < 4; ++t) acc += wt[0][t] * pc0[lin[0][t]];
        #pragma unroll
        for (int t = 0; t < 4; ++t) acc += wt[1][t] * pc1[lin[1][t]];
        ob[(size_t)c * HW] = acc;
    }
}

extern "C" void kernel_launch(void* const* d_in, const int* in_sizes, int n_in,
                              void* d_out, int out_size, void* d_ws, size_t ws_size,
                              hipStream_t stream) {
    const float* pred = (const float*)d_in[0];   // [B,R,C,H,W] fp32
    const float* mv   = (const float*)d_in[1];   // [B,R,2,H,W] fp32
    const float* wgt  = (const float*)d_in[2];   // [B,R,1,H,W] fp32
    float* out = (float*)d_out;                  // [B,C,H,W] fp32

    int total = B * HW;                          // one thread per (b,y,x)
    int block = 256;
    int grid = (total + block - 1) / block;      // 2048 blocks
    mc_warp_kernel<<<grid, block, 0, stream>>>(pred, mv, wgt, out);
}